// Round 3
// baseline (1055.769 us; speedup 1.0000x reference)
//
#include <hip/hip_runtime.h>
#include <hip/hip_bf16.h>
#include <math.h>

// Problem constants (from reference setup_inputs)
constexpr int N_NODES = 50000;
constexpr int E_EDGES = 800000;
constexpr int E_TOT   = E_EDGES + N_NODES;   // + self loops
constexpr int F_IN  = 1433;
constexpr int KPAD1 = 1440;                  // F_IN padded to mult of 32
constexpr int F1 = 512;
constexpr int F2 = 256;
constexpr int NC = 7;
constexpr int MAXDEG = 1024;
constexpr float NEG_SLOPE = 0.2f;

typedef unsigned short u16;
typedef unsigned int   u32;
typedef short s16x8 __attribute__((ext_vector_type(8)));   // 8 bf16 = 4 VGPRs
typedef float f32x4 __attribute__((ext_vector_type(4)));
// x rows are 1433 f32 = 5732 B -> only 4-B aligned; reduced-alignment vec type
typedef float float4a __attribute__((ext_vector_type(4), aligned(4)));

__device__ inline u16 f2b(float f) {                 // fp32 -> bf16 bits, RNE
    u32 u = __float_as_uint(f);
    u32 r = (u + 0x7fffu + ((u >> 16) & 1u)) >> 16;
    return (u16)r;
}
__device__ inline float b2f(u16 b) { return __uint_as_float(((u32)b) << 16); }

__device__ inline u32 pkbf16(float lo, float hi) {   // v_cvt_pk_bf16_f32 (RNE)
    union { __hip_bfloat162 h; u32 u; } c;
    c.h = __float22bfloat162_rn(make_float2(lo, hi));
    return c.u;
}

__device__ inline void gload_lds16(const void* g, void* l) {
    __builtin_amdgcn_global_load_lds(
        (const __attribute__((address_space(1))) u32*)g,
        (__attribute__((address_space(3))) u32*)l, 16, 0, 0);
}

// Guarded 8-f32 load (columns >= F_IN read as exact 0).
// Aligned fast path uses NON-TEMPORAL loads: x is 286 MB streamed exactly
// once with zero reuse -- keep it from evicting the L2-resident W1t.
__device__ inline void loadA8_nt(const float* p, int gk, float4a& v0, float4a& v1) {
    if (gk + 8 <= F_IN) {
        v0 = __builtin_nontemporal_load((const float4a*)p);
        v1 = __builtin_nontemporal_load((const float4a*)(p + 4));
    } else {
#pragma unroll
        for (int i = 0; i < 4; ++i) v0[i] = (gk + i < F_IN) ? p[i] : 0.f;
#pragma unroll
        for (int i = 0; i < 4; ++i) v1[i] = (gk + 4 + i < F_IN) ? p[4 + i] : 0.f;
    }
}

// ---------------------------------------------------------------------------
// CSR build: histogram -> exclusive scan -> scatter
// ---------------------------------------------------------------------------
__global__ void count_dst_kernel(const int* __restrict__ dst, int* __restrict__ counts) {
    int i = blockIdx.x * blockDim.x + threadIdx.x;
    if (i < E_TOT) {
        int d = (i < E_EDGES) ? dst[i] : (i - E_EDGES);
        atomicAdd(&counts[d], 1);
    }
}

__global__ __launch_bounds__(1024) void scan_kernel(const int* __restrict__ counts,
                                                    int* __restrict__ row_ptr, int n) {
    __shared__ int part[1024];
    int t = threadIdx.x;
    int chunk = (n + 1023) / 1024;
    int lo = t * chunk;
    int hi = min(lo + chunk, n);
    int s = 0;
    for (int i = lo; i < hi; ++i) s += counts[i];
    part[t] = s;
    __syncthreads();
    for (int off = 1; off < 1024; off <<= 1) {
        int v = 0;
        if (t >= off) v = part[t - off];
        __syncthreads();
        part[t] += v;
        __syncthreads();
    }
    int run = part[t] - s;
    for (int i = lo; i < hi; ++i) { row_ptr[i] = run; run += counts[i]; }
    if (t == 1023) row_ptr[n] = part[1023];
}

__global__ void scatter_kernel(const int* __restrict__ src, const int* __restrict__ dst,
                               const int* __restrict__ row_ptr, int* __restrict__ fill,
                               int* __restrict__ col) {
    int i = blockIdx.x * blockDim.x + threadIdx.x;
    if (i < E_TOT) {
        int s = (i < E_EDGES) ? src[i] : (i - E_EDGES);
        int d = (i < E_EDGES) ? dst[i] : (i - E_EDGES);
        int p = row_ptr[d] + atomicAdd(&fill[d], 1);
        col[p] = s;
    }
}

// W [K][Nn] f32 -> Wt [Nn][KP] bf16 transposed (zero pad K)
__global__ void convert_wt_kernel(const float* __restrict__ W, u32* __restrict__ Wt,
                                  int K, int Nn, int KP) {
    int p = blockIdx.x * blockDim.x + threadIdx.x;
    int ppr = KP / 2;
    if (p >= Nn * ppr) return;
    int n = p / ppr;
    int k = (p - n * ppr) * 2;
    float v0 = (k + 0 < K) ? W[(size_t)(k + 0) * Nn + n] : 0.f;
    float v1 = (k + 1 < K) ? W[(size_t)(k + 1) * Nn + n] : 0.f;
    Wt[p] = (u32)f2b(v0) | ((u32)f2b(v1) << 16);
}

// ---------------------------------------------------------------------------
// Layer-1 fused GEMM: C[M][512](bf16) = A[M][1433](f32) @ W1t[512][1440]^T
// v4 = v2 structure (single-barrier dbuf; R1's 201us version) + non-temporal
// A loads / C stores.
// Theory: A streams 366KB/block x ~64 resident blocks/XCD through each 4MB
// L2, evicting the 1.47MB W1t that all 782 blocks reread (1.15 GB refetch).
// nt on A/C keeps W1t L2-resident -> B refetch at L2 rate instead of LLC.
// Output bit-identical (same RNE cvt, same operand values).
// ---------------------------------------------------------------------------
__global__ __launch_bounds__(256, 2) void gemm1_fused(const float* __restrict__ A,
                                                      const u16* __restrict__ Bt,
                                                      u16* __restrict__ C) {
    constexpr int M = N_NODES;
    constexpr int ABUF = 64 * 32;     // u16 per A buffer (4 KB)
    constexpr int BBUF = 512 * 32;    // u16 per B buffer (32 KB)
    __shared__ u16 sA[2 * ABUF];
    __shared__ u16 sB[2 * BBUF];
    int tid  = threadIdx.x;
    int wave = tid >> 6;
    int lane = tid & 63;
    int quad = lane >> 4;
    int lm   = lane & 15;
    int m0 = blockIdx.x * 64;

    // ---- A staging: thread t owns row t>>2 (of 64), fetches swizzled slot
    int arow  = min(m0 + (tid >> 2), M - 1);
    int aslot = (tid & 3) ^ ((tid >> 3) & 3);          // global 8-f32 slot
    const float* xcol = A + (size_t)arow * F_IN + aslot * 8;
    int acolbase = aslot * 8;

    // ---- B staging: 32 chunks of (16 rows x 32 bf16 = 1 KB); wave w: 8w..8w+7
    // gload_lds writes lane l -> chunk byte l*16 = (row l>>2, slot l&3);
    // source reads swizzled slot so LDS(row,s) holds G(row, s^((row>>1)&3)).
    const u16* gB[8];
    u16* lB[8];
#pragma unroll
    for (int c = 0; c < 8; ++c) {
        int chunk = wave * 8 + c;
        int row  = chunk * 16 + (lane >> 2);
        int slot = (lane & 3) ^ ((lane >> 3) & 3);
        gB[c] = Bt + (size_t)row * KPAD1 + slot * 8;
        lB[c] = &sB[chunk * 512];
    }

    f32x4 acc[4][8];
#pragma unroll
    for (int i = 0; i < 4; ++i)
#pragma unroll
        for (int j = 0; j < 8; ++j) acc[i][j] = (f32x4){0.f, 0.f, 0.f, 0.f};

    // swizzled read slot offset (u16 units) for fragment loads
    int rdoff = (quad ^ ((lm >> 1) & 3)) * 8;

    // ---- prologue: stage k=0 into buffer 0
    {
#pragma unroll
        for (int c = 0; c < 8; ++c) gload_lds16(gB[c], lB[c]);
        float4a a0, a1;
        loadA8_nt(xcol, acolbase, a0, a1);
        uint4 pk;
        pk.x = pkbf16(a0[0], a0[1]); pk.y = pkbf16(a0[2], a0[3]);
        pk.z = pkbf16(a1[0], a1[1]); pk.w = pkbf16(a1[2], a1[3]);
        *(uint4*)&sA[tid * 8] = pk;
    }
    __syncthreads();

    int cur = 0;
    for (int k0 = 0; k0 < KPAD1; k0 += 32) {
        int kn = k0 + 32;
        bool hasnext = kn < KPAD1;
        int nxt = cur ^ 1;

        // issue next-step loads first (latency hides under current compute)
        float4a a0, a1;
        if (hasnext) {
#pragma unroll
            for (int c = 0; c < 8; ++c) gload_lds16(gB[c] + kn, lB[c] + nxt * BBUF);
            loadA8_nt(xcol + kn, acolbase + kn, a0, a1);
        }

        // compute current buffer
        const u16* sAc = &sA[cur * ABUF];
        const u16* sBc = &sB[cur * BBUF];
        s16x8 af[4], bf[8];
#pragma unroll
        for (int mt = 0; mt < 4; ++mt)
            af[mt] = *(const s16x8*)&sAc[(mt * 16 + lm) * 32 + rdoff];
#pragma unroll
        for (int nt = 0; nt < 8; ++nt)
            bf[nt] = *(const s16x8*)&sBc[(wave * 128 + nt * 16 + lm) * 32 + rdoff];
#pragma unroll
        for (int mt = 0; mt < 4; ++mt)
#pragma unroll
            for (int nt = 0; nt < 8; ++nt)
                acc[mt][nt] = __builtin_amdgcn_mfma_f32_16x16x32_bf16(
                    af[mt], bf[nt], acc[mt][nt], 0, 0, 0);

        // write next A tile late (regs have arrived by now)
        if (hasnext) {
            uint4 pk;
            pk.x = pkbf16(a0[0], a0[1]); pk.y = pkbf16(a0[2], a0[3]);
            pk.z = pkbf16(a1[0], a1[1]); pk.w = pkbf16(a1[2], a1[3]);
            *(uint4*)&sA[nxt * ABUF + tid * 8] = pk;
        }
        __syncthreads();
        cur = nxt;
    }

    // C write: col = lane&15, row = quad*4 + reg (non-temporal: consumed by
    // later kernels, 51MB stream -- keep it out of L2 while blocks still run)
#pragma unroll
    for (int mt = 0; mt < 4; ++mt) {
        int mbase = m0 + mt * 16 + quad * 4;
#pragma unroll
        for (int nt = 0; nt < 8; ++nt) {
            int n = wave * 128 + nt * 16 + lm;
#pragma unroll
            for (int r = 0; r < 4; ++r) {
                int m = mbase + r;
                if (m < M)
                    __builtin_nontemporal_store(f2b(acc[mt][nt][r]),
                                                &C[(size_t)m * F1 + n]);
            }
        }
    }
}

// ---------------------------------------------------------------------------
// MFMA bf16 GEMM (layer 2): C = A bf16 @ Bt^T  (+ R1's slot swizzle)
// ---------------------------------------------------------------------------
__global__ __launch_bounds__(256) void mfma_gemm_bt(const u16* __restrict__ A,
                                                    const u16* __restrict__ Bt,
                                                    u16* __restrict__ C,
                                                    int M, int N, int K) {
    __shared__ u16 sA[128 * 32];
    __shared__ u16 sB[128 * 32];
    int tid  = threadIdx.x;
    int wave = tid >> 6;
    int lane = tid & 63;
    int quad = lane >> 4;
    int lm   = lane & 15;
    int wm = wave & 1;
    int wn = wave >> 1;
    int m0 = blockIdx.y * 128;
    int n0 = blockIdx.x * 128;

    int ch0 = wave * 2, ch1 = wave * 2 + 1;
    int rsub = lane >> 2;
    int slot = (lane & 3) ^ ((lane >> 3) & 3);   // swizzled source slot
    int csub = slot * 8;
    int ar0 = min(m0 + ch0 * 16 + rsub, M - 1);
    int ar1 = min(m0 + ch1 * 16 + rsub, M - 1);
    int br0 = n0 + ch0 * 16 + rsub;
    int br1 = n0 + ch1 * 16 + rsub;
    const u16* gA0 = A + (size_t)ar0 * K + csub;
    const u16* gA1 = A + (size_t)ar1 * K + csub;
    const u16* gB0 = Bt + (size_t)br0 * K + csub;
    const u16* gB1 = Bt + (size_t)br1 * K + csub;

    f32x4 acc[4][4];
#pragma unroll
    for (int i = 0; i < 4; ++i)
#pragma unroll
        for (int j = 0; j < 4; ++j) acc[i][j] = (f32x4){0.f, 0.f, 0.f, 0.f};

    int rdoff = (quad ^ ((lm >> 1) & 3)) * 8;    // swizzled read slot

    for (int k0 = 0; k0 < K; k0 += 32) {
        gload_lds16(gA0 + k0, &sA[ch0 * 512]);
        gload_lds16(gA1 + k0, &sA[ch1 * 512]);
        gload_lds16(gB0 + k0, &sB[ch0 * 512]);
        gload_lds16(gB1 + k0, &sB[ch1 * 512]);
        __syncthreads();

        s16x8 af[4], bf[4];
#pragma unroll
        for (int mt = 0; mt < 4; ++mt)
            af[mt] = *(const s16x8*)&sA[(wm * 64 + mt * 16 + lm) * 32 + rdoff];
#pragma unroll
        for (int nt = 0; nt < 4; ++nt)
            bf[nt] = *(const s16x8*)&sB[(wn * 64 + nt * 16 + lm) * 32 + rdoff];
#pragma unroll
        for (int mt = 0; mt < 4; ++mt)
#pragma unroll
            for (int nt = 0; nt < 4; ++nt)
                acc[mt][nt] = __builtin_amdgcn_mfma_f32_16x16x32_bf16(
                    af[mt], bf[nt], acc[mt][nt], 0, 0, 0);
        __syncthreads();
    }

#pragma unroll
    for (int mt = 0; mt < 4; ++mt) {
        int mbase = m0 + wm * 64 + mt * 16 + quad * 4;
#pragma unroll
        for (int nt = 0; nt < 4; ++nt) {
            int n = n0 + wn * 64 + nt * 16 + lm;
#pragma unroll
            for (int r = 0; r < 4; ++r) {
                int m = mbase + r;
                if (m < M) C[(size_t)m * N + n] = f2b(acc[mt][nt][r]);
            }
        }
    }
}

// ---------------------------------------------------------------------------
// Per-node attention scores, bf16 h. One wave per node.
// ---------------------------------------------------------------------------
template <int F>
__global__ __launch_bounds__(256) void scores_bf16_kernel(const u16* __restrict__ h,
                                                          const float* __restrict__ a_src,
                                                          const float* __restrict__ a_dst,
                                                          float* __restrict__ s_src,
                                                          float* __restrict__ s_dst, int n) {
    int gwid = (blockIdx.x * blockDim.x + threadIdx.x) >> 6;
    int lane = threadIdx.x & 63;
    if (gwid >= n) return;
    const u32* row = (const u32*)(h + (size_t)gwid * F);
    float acc1 = 0.f, acc2 = 0.f;
    for (int p = lane; p < F / 2; p += 64) {
        u32 u = row[p];
        float v0 = b2f((u16)(u & 0xffff));
        float v1 = b2f((u16)(u >> 16));
        acc1 += v0 * a_src[2 * p] + v1 * a_src[2 * p + 1];
        acc2 += v0 * a_dst[2 * p] + v1 * a_dst[2 * p + 1];
    }
#pragma unroll
    for (int o = 32; o; o >>= 1) {
        acc1 += __shfl_xor(acc1, o);
        acc2 += __shfl_xor(acc2, o);
    }
    if (lane == 0) { s_src[gwid] = acc1; s_dst[gwid] = acc2; }
}

// fp32 variant (layer 3, F=NC)
template <int F>
__global__ __launch_bounds__(256) void scores_kernel(const float* __restrict__ h,
                                                     const float* __restrict__ a_src,
                                                     const float* __restrict__ a_dst,
                                                     float* __restrict__ s_src,
                                                     float* __restrict__ s_dst, int n) {
    int gwid = (blockIdx.x * blockDim.x + threadIdx.x) >> 6;
    int lane = threadIdx.x & 63;
    if (gwid >= n) return;
    const float* row = h + (size_t)gwid * F;
    float acc1 = 0.f, acc2 = 0.f;
    for (int f = lane; f < F; f += 64) {
        float v = row[f];
        acc1 += v * a_src[f];
        acc2 += v * a_dst[f];
    }
#pragma unroll
    for (int o = 32; o; o >>= 1) {
        acc1 += __shfl_xor(acc1, o);
        acc2 += __shfl_xor(acc2, o);
    }
    if (lane == 0) { s_src[gwid] = acc1; s_dst[gwid] = acc2; }
}

// ---------------------------------------------------------------------------
// CSR aggregation + segment softmax, bf16 h: ONE WAVE PER NODE, online
// softmax (running max m / denom with rescale). No LDS, no barriers, no
// MAXDEG cap, no serial wave-0 phase.
// ---------------------------------------------------------------------------
template <int F, bool OUT_BF16>
__global__ __launch_bounds__(256) void agg_online_kernel(
        const u16* __restrict__ h, const float* __restrict__ s_src,
        const float* __restrict__ s_dst, const float* __restrict__ bias,
        const int* __restrict__ row_ptr, const int* __restrict__ col,
        void* __restrict__ out, int n) {
    constexpr int UPL = F / 128;   // u32 per lane: 4 (F=512) or 2 (F=256)
    int gwid = (blockIdx.x * blockDim.x + threadIdx.x) >> 6;
    int lane = threadIdx.x & 63;
    if (gwid >= n) return;
    int beg = row_ptr[gwid];
    int end = row_ptr[gwid + 1];
    float sd = s_dst[gwid];
    const u32* hw = (const u32*)h;
    int loff = lane * UPL;

    float m = -1e30f, denom = 0.f;
    float acc[2 * UPL];
#pragma unroll
    for (int e = 0; e < 2 * UPL; ++e) acc[e] = 0.f;

    int j = beg;
    for (; j + 2 <= end; j += 2) {
        int c0 = col[j], c1 = col[j + 1];
        const u32* r0 = hw + (size_t)c0 * (F / 2) + loff;
        const u32* r1 = hw + (size_t)c1 * (F / 2) + loff;
        u32 v0[UPL], v1[UPL];
        if constexpr (UPL == 4) {
            uint4 q0 = *(const uint4*)r0; v0[0]=q0.x; v0[1]=q0.y; v0[2]=q0.z; v0[3]=q0.w;
            uint4 q1 = *(const uint4*)r1; v1[0]=q1.x; v1[1]=q1.y; v1[2]=q1.z; v1[3]=q1.w;
        } else {
            uint2 q0 = *(const uint2*)r0; v0[0]=q0.x; v0[1]=q0.y;
            uint2 q1 = *(const uint2*)r1; v1[0]=q1.x; v1[1]=q1.y;
        }
        float e0 = s_src[c0] + sd; e0 = (e0 > 0.f) ? e0 : NEG_SLOPE * e0;
        float e1 = s_src[c1] + sd; e1 = (e1 > 0.f) ? e1 : NEG_SLOPE * e1;
        float mn = fmaxf(fmaxf(m, e0), e1);
        float sc = expf(m - mn);
        float w0 = expf(e0 - mn);
        float w1 = expf(e1 - mn);
        denom = denom * sc + w0 + w1;
        m = mn;
#pragma unroll
        for (int u = 0; u < UPL; ++u) {
            acc[2*u]   = acc[2*u]   * sc + w0 * b2f((u16)(v0[u] & 0xffff))
                                         + w1 * b2f((u16)(v1[u] & 0xffff));
            acc[2*u+1] = acc[2*u+1] * sc + w0 * b2f((u16)(v0[u] >> 16))
                                         + w1 * b2f((u16)(v1[u] >> 16));
        }
    }
    if (j < end) {
        int c0 = col[j];
        const u32* r0 = hw + (size_t)c0 * (F / 2) + loff;
        u32 v0[UPL];
        if constexpr (UPL == 4) {
            uint4 q0 = *(const uint4*)r0; v0[0]=q0.x; v0[1]=q0.y; v0[2]=q0.z; v0[3]=q0.w;
        } else {
            uint2 q0 = *(const uint2*)r0; v0[0]=q0.x; v0[1]=q0.y;
        }
        float e0 = s_src[c0] + sd; e0 = (e0 > 0.f) ? e0 : NEG_SLOPE * e0;
        float mn = fmaxf(m, e0);
        float sc = expf(m - mn);
        float w0 = expf(e0 - mn);
        denom = denom * sc + w0;
        m = mn;
#pragma unroll
        for (int u = 0; u < UPL; ++u) {
            acc[2*u]   = acc[2*u]   * sc + w0 * b2f((u16)(v0[u] & 0xffff));
            acc[2*u+1] = acc[2*u+1] * sc + w0 * b2f((u16)(v0[u] >> 16));
        }
    }

    float inv = 1.0f / denom;
    if constexpr (OUT_BF16) {
        const float2* bp2 = (const float2*)bias;
        u32 ov[UPL];
#pragma unroll
        for (int u = 0; u < UPL; ++u) {
            float2 bb = bp2[loff + u];
            float v0 = fmaxf(acc[2*u]   * inv + bb.x, 0.f);
            float v1 = fmaxf(acc[2*u+1] * inv + bb.y, 0.f);
            ov[u] = pkbf16(v0, v1);
        }
        u32* op = (u32*)out + (size_t)gwid * (F / 2) + loff;
        if constexpr (UPL == 4) {
            uint4 q = {ov[0], ov[1], ov[2], ov[3]};
            *(uint4*)op = q;
        } else {
            uint2 q = {ov[0], ov[1]};
            *(uint2*)op = q;
        }
    } else {
        // UPL == 2: 4 consecutive f32 per lane
        const float* bp = bias + 2 * loff;
        float4 q = { fmaxf(acc[0] * inv + bp[0], 0.f),
                     fmaxf(acc[1] * inv + bp[1], 0.f),
                     fmaxf(acc[2] * inv + bp[2], 0.f),
                     fmaxf(acc[3] * inv + bp[3], 0.f) };
        *(float4*)((float*)out + (size_t)gwid * F + 2 * loff) = q;
    }
}

// ---------------------------------------------------------------------------
// Layer-3 aggregation: lane-per-edge, fused log_softmax. One wave per node.
// ---------------------------------------------------------------------------
__global__ __launch_bounds__(64) void agg_lsm7_kernel(const float* __restrict__ h,
                                                      const float* __restrict__ s_src,
                                                      const float* __restrict__ s_dst,
                                                      const float* __restrict__ bias,
                                                      const int* __restrict__ row_ptr,
                                                      const int* __restrict__ col,
                                                      float* __restrict__ out) {
    int node = blockIdx.x;
    int lane = threadIdx.x;
    int beg = row_ptr[node];
    int deg = min(row_ptr[node + 1] - beg, MAXDEG);

    __shared__ float w[MAXDEG];
    __shared__ int cs[MAXDEG];

    float sd = s_dst[node];
    float m = -1e30f;
    for (int j = lane; j < deg; j += 64) {
        int s = col[beg + j];
        cs[j] = s;
        float e = s_src[s] + sd;
        e = (e > 0.f) ? e : NEG_SLOPE * e;
        w[j] = e;
        m = fmaxf(m, e);
    }
#pragma unroll
    for (int o = 32; o; o >>= 1) m = fmaxf(m, __shfl_xor(m, o));
    float sum = 0.f;
    for (int j = lane; j < deg; j += 64) {
        float v = expf(w[j] - m);
        w[j] = v;
        sum += v;
    }
#pragma unroll
    for (int o = 32; o; o >>= 1) sum += __shfl_xor(sum, o);
    float inv = 1.0f / sum;

    float a[NC];
#pragma unroll
    for (int f = 0; f < NC; ++f) a[f] = 0.f;
    for (int j = lane; j < deg; j += 64) {
        float wg = w[j] * inv;
        const float* row = h + (size_t)cs[j] * NC;
#pragma unroll
        for (int f = 0; f < NC; ++f) a[f] += wg * row[f];
    }
#pragma unroll
    for (int f = 0; f < NC; ++f)
#pragma unroll
        for (int o = 32; o; o >>= 1) a[f] += __shfl_xor(a[f], o);

    if (lane == 0) {
        float vals[NC];
        float mx = -1e30f;
#pragma unroll
        for (int f = 0; f < NC; ++f) { vals[f] = a[f] + bias[f]; mx = fmaxf(mx, vals[f]); }
        float ssum = 0.f;
#pragma unroll
        for (int f = 0; f < NC; ++f) ssum += expf(vals[f] - mx);
        float lse = mx + logf(ssum);
#pragma unroll
        for (int f = 0; f < NC; ++f) out[(size_t)node * NC + f] = vals[f] - lse;
    }
}

// ---------------------------------------------------------------------------
// GEMM3: out[N,7] = A[N,256] f32 @ W[256,7] f32. One wave per node.
// ---------------------------------------------------------------------------
__global__ __launch_bounds__(256) void gemm3_kernel(const float* __restrict__ A,
                                                    const float* __restrict__ W,
                                                    float* __restrict__ out, int n) {
    __shared__ float sW[F2 * NC];
    for (int i = threadIdx.x; i < F2 * NC; i += blockDim.x) sW[i] = W[i];
    __syncthreads();
    int gwid = (blockIdx.x * blockDim.x + threadIdx.x) >> 6;
    int lane = threadIdx.x & 63;
    if (gwid >= n) return;
    const float* row = A + (size_t)gwid * F2;
    float4 v = *(const float4*)(row + lane * 4);
    float res = 0.f;
#pragma unroll
    for (int c = 0; c < NC; ++c) {
        float p = v.x * sW[(lane * 4 + 0) * NC + c] + v.y * sW[(lane * 4 + 1) * NC + c] +
                  v.z * sW[(lane * 4 + 2) * NC + c] + v.w * sW[(lane * 4 + 3) * NC + c];
#pragma unroll
        for (int o = 32; o; o >>= 1) p += __shfl_xor(p, o);
        if (lane == c) res = p;
    }
    if (lane < NC) out[(size_t)gwid * NC + lane] = res;
}

// ---------------------------------------------------------------------------
extern "C" void kernel_launch(void* const* d_in, const int* in_sizes, int n_in,
                              void* d_out, int out_size, void* d_ws, size_t ws_size,
                              hipStream_t stream) {
    const float* x   = (const float*)d_in[0];
    const int* ei    = (const int*)d_in[1];
    const int* src   = ei;
    const int* dst   = ei + E_EDGES;
    const float* W1  = (const float*)d_in[2];
    const float* as1 = (const float*)d_in[3];
    const float* ad1 = (const float*)d_in[4];
    const float* b1  = (const float*)d_in[5];
    const float* W2  = (const float*)d_in[6];
    const float* as2 = (const float*)d_in[7];
    const float* ad2 = (const float*)d_in[8];
    const float* b2  = (const float*)d_in[9];
    const float* W3  = (const float*)d_in[10];
    const float* as3 = (const float*)d_in[11];
    const float* ad3 = (const float*)d_in[12];
    const float* b3  = (const float*)d_in[13];
    float* outp = (float*)d_out;

    // ---------------- workspace layout (byte offsets) ----------------------
    char* base = (char*)d_ws;
    u16*  a1b = (u16*)base;                                   // [N][512]  bf16
    u16*  h2b = (u16*)(base + 51200000);                      // [N][256]  bf16
    float* a2 = (float*)(base + 76800000);                    // [N][256]  f32
    float* h3 = (float*)(base + 128000000);                   // [N][7]    f32
    u16*  h1b = (u16*)(base + 144000000);                     // [N][512]  bf16
    u16*  W1t = (u16*)(base + 195200000);                     // [512][1440] bf16
    u16*  W2t = (u16*)(base + 196674560);                     // [256][512]  bf16
    float* ssrc = (float*)(base + 196936704);                 // [N]
    float* sdst = (float*)(base + 197136704);                 // [N]
    int* row_ptr = (int*)(base + 197336704);                  // [N+1]
    int* counts  = (int*)(base + 197536708);                  // [N]
    int* fill    = (int*)(base + 197736708);                  // [N]
    int* col     = (int*)(base + 197936708);                  // [E_TOT]

    hipMemsetAsync(counts, 0, sizeof(int) * N_NODES, stream);
    hipMemsetAsync(fill, 0, sizeof(int) * N_NODES, stream);

    // CSR build
    {
        int blk = 256;
        int grid = (E_TOT + blk - 1) / blk;
        count_dst_kernel<<<grid, blk, 0, stream>>>(dst, counts);
        scan_kernel<<<1, 1024, 0, stream>>>(counts, row_ptr, N_NODES);
        scatter_kernel<<<grid, blk, 0, stream>>>(src, dst, row_ptr, fill, col);
    }

    // weight bf16 conversions
    {
        int nw1 = F1 * (KPAD1 / 2);
        convert_wt_kernel<<<(nw1 + 255) / 256, 256, 0, stream>>>(W1, (u32*)W1t, F_IN, F1, KPAD1);
        int nw2 = F2 * (F1 / 2);
        convert_wt_kernel<<<(nw2 + 255) / 256, 256, 0, stream>>>(W2, (u32*)W2t, F1, F2, F1);
    }

    int waves_grid = (N_NODES + 3) / 4;
    int mblocks = (N_NODES + 127) / 128;  // 391

    // ---- Layer 1 (fused f32->bf16 conversion; x read from HBM once)
    {
        int grid1 = (N_NODES + 63) / 64;  // 782
        gemm1_fused<<<grid1, 256, 0, stream>>>(x, W1t, h1b);
        scores_bf16_kernel<F1><<<waves_grid, 256, 0, stream>>>(h1b, as1, ad1, ssrc, sdst, N_NODES);
        agg_online_kernel<F1, true><<<waves_grid, 256, 0, stream>>>(
            h1b, ssrc, sdst, b1, row_ptr, col, a1b, N_NODES);
    }
    // ---- Layer 2
    {
        dim3 grid(F2 / 128, mblocks);
        mfma_gemm_bt<<<grid, 256, 0, stream>>>(a1b, W2t, h2b, N_NODES, F2, F1);
        scores_bf16_kernel<F2><<<waves_grid, 256, 0, stream>>>(h2b, as2, ad2, ssrc, sdst, N_NODES);
        agg_online_kernel<F2, false><<<waves_grid, 256, 0, stream>>>(
            h2b, ssrc, sdst, b2, row_ptr, col, a2, N_NODES);
    }
    // ---- Layer 3 (fp32)
    {
        gemm3_kernel<<<waves_grid, 256, 0, stream>>>(a2, W3, h3, N_NODES);
        scores_kernel<NC><<<waves_grid, 256, 0, stream>>>(h3, as3, ad3, ssrc, sdst, N_NODES);
        agg_lsm7_kernel<<<N_NODES, 64, 0, stream>>>(
            h3, ssrc, sdst, b3, row_ptr, col, outp);
    }
}

// Round 4
// 1041.587 us; speedup vs baseline: 1.0136x; 1.0136x over previous
//
#include <hip/hip_runtime.h>
#include <hip/hip_bf16.h>
#include <math.h>

// Problem constants (from reference setup_inputs)
constexpr int N_NODES = 50000;
constexpr int E_EDGES = 800000;
constexpr int E_TOT   = E_EDGES + N_NODES;   // + self loops
constexpr int F_IN  = 1433;
constexpr int KPAD1 = 1440;                  // F_IN padded to mult of 32
constexpr int F1 = 512;
constexpr int F2 = 256;
constexpr int NC = 7;
constexpr int MAXDEG = 1024;
constexpr float NEG_SLOPE = 0.2f;

typedef unsigned short u16;
typedef unsigned int   u32;
typedef short s16x8 __attribute__((ext_vector_type(8)));   // 8 bf16 = 4 VGPRs
typedef float f32x4 __attribute__((ext_vector_type(4)));
// x rows are 1433 f32 = 5732 B -> only 4-B aligned; reduced-alignment vec type
typedef float float4a __attribute__((ext_vector_type(4), aligned(4)));

__device__ inline u16 f2b(float f) {                 // fp32 -> bf16 bits, RNE
    u32 u = __float_as_uint(f);
    u32 r = (u + 0x7fffu + ((u >> 16) & 1u)) >> 16;
    return (u16)r;
}
__device__ inline float b2f(u16 b) { return __uint_as_float(((u32)b) << 16); }

__device__ inline u32 pkbf16(float lo, float hi) {   // v_cvt_pk_bf16_f32 (RNE)
    union { __hip_bfloat162 h; u32 u; } c;
    c.h = __float22bfloat162_rn(make_float2(lo, hi));
    return c.u;
}

__device__ inline void gload_lds16(const void* g, void* l) {
    __builtin_amdgcn_global_load_lds(
        (const __attribute__((address_space(1))) u32*)g,
        (__attribute__((address_space(3))) u32*)l, 16, 0, 0);
}

// Guarded 8-f32 load (columns >= F_IN read as exact 0). Plain loads:
// R3 showed non-temporal hints are a ~15% regression here.
__device__ inline void loadA8(const float* p, int gk, float4a& v0, float4a& v1) {
    if (gk + 8 <= F_IN) {
        v0 = *(const float4a*)p;
        v1 = *(const float4a*)(p + 4);
    } else {
#pragma unroll
        for (int i = 0; i < 4; ++i) v0[i] = (gk + i < F_IN) ? p[i] : 0.f;
#pragma unroll
        for (int i = 0; i < 4; ++i) v1[i] = (gk + 4 + i < F_IN) ? p[4 + i] : 0.f;
    }
}

// ---------------------------------------------------------------------------
// CSR build: histogram -> exclusive scan -> scatter
// ---------------------------------------------------------------------------
__global__ void count_dst_kernel(const int* __restrict__ dst, int* __restrict__ counts) {
    int i = blockIdx.x * blockDim.x + threadIdx.x;
    if (i < E_TOT) {
        int d = (i < E_EDGES) ? dst[i] : (i - E_EDGES);
        atomicAdd(&counts[d], 1);
    }
}

__global__ __launch_bounds__(1024) void scan_kernel(const int* __restrict__ counts,
                                                    int* __restrict__ row_ptr, int n) {
    __shared__ int part[1024];
    int t = threadIdx.x;
    int chunk = (n + 1023) / 1024;
    int lo = t * chunk;
    int hi = min(lo + chunk, n);
    int s = 0;
    for (int i = lo; i < hi; ++i) s += counts[i];
    part[t] = s;
    __syncthreads();
    for (int off = 1; off < 1024; off <<= 1) {
        int v = 0;
        if (t >= off) v = part[t - off];
        __syncthreads();
        part[t] += v;
        __syncthreads();
    }
    int run = part[t] - s;
    for (int i = lo; i < hi; ++i) { row_ptr[i] = run; run += counts[i]; }
    if (t == 1023) row_ptr[n] = part[1023];
}

__global__ void scatter_kernel(const int* __restrict__ src, const int* __restrict__ dst,
                               const int* __restrict__ row_ptr, int* __restrict__ fill,
                               int* __restrict__ col) {
    int i = blockIdx.x * blockDim.x + threadIdx.x;
    if (i < E_TOT) {
        int s = (i < E_EDGES) ? src[i] : (i - E_EDGES);
        int d = (i < E_EDGES) ? dst[i] : (i - E_EDGES);
        int p = row_ptr[d] + atomicAdd(&fill[d], 1);
        col[p] = s;
    }
}

// W [K][Nn] f32 -> Wt [Nn][KP] bf16 transposed (zero pad K)
__global__ void convert_wt_kernel(const float* __restrict__ W, u32* __restrict__ Wt,
                                  int K, int Nn, int KP) {
    int p = blockIdx.x * blockDim.x + threadIdx.x;
    int ppr = KP / 2;
    if (p >= Nn * ppr) return;
    int n = p / ppr;
    int k = (p - n * ppr) * 2;
    float v0 = (k + 0 < K) ? W[(size_t)(k + 0) * Nn + n] : 0.f;
    float v1 = (k + 1 < K) ? W[(size_t)(k + 1) * Nn + n] : 0.f;
    Wt[p] = (u32)f2b(v0) | ((u32)f2b(v1) << 16);
}

// ---------------------------------------------------------------------------
// Layer-1 fused GEMM: C[M][512](bf16) = A[M][1433](f32) @ W1t[512][1440]^T
// v5: occupancy-targeted retile. R3 proved the kernel is latency-bound
// (runtime invariant to +-50% memory traffic): acc[4][8]=128 AGPR + 108
// VGPR = 236 regs/lane -> only 8 waves/CU; nothing to run during the
// per-step barrier stall, and grid 782 over 512 slots idles half the
// machine in round 2.
// Fix: 64M x 256N tile, 4 waves each owning 64x64 -> acc=64 AGPR,
// ~150-165 combined -> 12 waves/CU (3 blocks), LDS 40 KB. Grid 1564
// (2 N-halves x 782 M-blocks) -> 2.04 rounds, ~98% tail utilization.
// Cost: A fetched twice (+26us HBM time, overlapped). Same swizzles,
// same single-barrier dbuf loop; output bit-identical.
// ---------------------------------------------------------------------------
__global__ __launch_bounds__(256, 3) void gemm1_fused(const float* __restrict__ A,
                                                      const u16* __restrict__ Bt,
                                                      u16* __restrict__ C) {
    constexpr int M = N_NODES;
    constexpr int ABUF = 64 * 32;     // u16 per A buffer (4 KB)
    constexpr int BBUF = 256 * 32;    // u16 per B buffer (16 KB)
    __shared__ u16 sA[2 * ABUF];
    __shared__ u16 sB[2 * BBUF];
    int tid  = threadIdx.x;
    int wave = tid >> 6;
    int lane = tid & 63;
    int quad = lane >> 4;
    int lm   = lane & 15;
    int m0 = blockIdx.y * 64;
    int n0 = blockIdx.x * 256;

    // ---- A staging: thread t owns row t>>2 (of 64), fetches swizzled slot
    int arow  = min(m0 + (tid >> 2), M - 1);
    int aslot = (tid & 3) ^ ((tid >> 3) & 3);          // global 8-f32 slot
    const float* xcol = A + (size_t)arow * F_IN + aslot * 8;
    int acolbase = aslot * 8;

    // ---- B staging: 16 chunks of (16 rows x 32 bf16 = 1 KB); wave w stages
    // chunks 4w..4w+3 = exactly the 64 N-rows it reads (self-contained).
    // gload_lds writes lane l -> chunk byte l*16 = (row l>>2, slot l&3);
    // source reads swizzled slot so LDS(row,s) holds G(row, s^((row>>1)&3)).
    const u16* gB[4];
    u16* lB[4];
#pragma unroll
    for (int c = 0; c < 4; ++c) {
        int chunk = wave * 4 + c;
        int row  = chunk * 16 + (lane >> 2);
        int slot = (lane & 3) ^ ((lane >> 3) & 3);
        gB[c] = Bt + (size_t)(n0 + row) * KPAD1 + slot * 8;
        lB[c] = &sB[chunk * 512];
    }

    f32x4 acc[4][4];
#pragma unroll
    for (int i = 0; i < 4; ++i)
#pragma unroll
        for (int j = 0; j < 4; ++j) acc[i][j] = (f32x4){0.f, 0.f, 0.f, 0.f};

    // swizzled read slot offset (u16 units) for fragment loads
    int rdoff = (quad ^ ((lm >> 1) & 3)) * 8;

    // ---- prologue: stage k=0 into buffer 0
    {
#pragma unroll
        for (int c = 0; c < 4; ++c) gload_lds16(gB[c], lB[c]);
        float4a a0, a1;
        loadA8(xcol, acolbase, a0, a1);
        uint4 pk;
        pk.x = pkbf16(a0[0], a0[1]); pk.y = pkbf16(a0[2], a0[3]);
        pk.z = pkbf16(a1[0], a1[1]); pk.w = pkbf16(a1[2], a1[3]);
        *(uint4*)&sA[tid * 8] = pk;
    }
    __syncthreads();

    int cur = 0;
    for (int k0 = 0; k0 < KPAD1; k0 += 32) {
        int kn = k0 + 32;
        bool hasnext = kn < KPAD1;
        int nxt = cur ^ 1;

        // issue next-step loads first (latency hides under current compute)
        float4a a0, a1;
        if (hasnext) {
#pragma unroll
            for (int c = 0; c < 4; ++c) gload_lds16(gB[c] + kn, lB[c] + nxt * BBUF);
            loadA8(xcol + kn, acolbase + kn, a0, a1);
        }

        // compute current buffer
        const u16* sAc = &sA[cur * ABUF];
        const u16* sBc = &sB[cur * BBUF];
        s16x8 af[4], bf[4];
#pragma unroll
        for (int mt = 0; mt < 4; ++mt)
            af[mt] = *(const s16x8*)&sAc[(mt * 16 + lm) * 32 + rdoff];
#pragma unroll
        for (int nt = 0; nt < 4; ++nt)
            bf[nt] = *(const s16x8*)&sBc[(wave * 64 + nt * 16 + lm) * 32 + rdoff];
#pragma unroll
        for (int mt = 0; mt < 4; ++mt)
#pragma unroll
            for (int nt = 0; nt < 4; ++nt)
                acc[mt][nt] = __builtin_amdgcn_mfma_f32_16x16x32_bf16(
                    af[mt], bf[nt], acc[mt][nt], 0, 0, 0);

        // write next A tile late (regs have arrived by now)
        if (hasnext) {
            uint4 pk;
            pk.x = pkbf16(a0[0], a0[1]); pk.y = pkbf16(a0[2], a0[3]);
            pk.z = pkbf16(a1[0], a1[1]); pk.w = pkbf16(a1[2], a1[3]);
            *(uint4*)&sA[nxt * ABUF + tid * 8] = pk;
        }
        __syncthreads();
        cur = nxt;
    }

    // C write: col = lane&15, row = quad*4 + reg
#pragma unroll
    for (int mt = 0; mt < 4; ++mt) {
        int mbase = m0 + mt * 16 + quad * 4;
#pragma unroll
        for (int nt = 0; nt < 4; ++nt) {
            int n = n0 + wave * 64 + nt * 16 + lm;
#pragma unroll
            for (int r = 0; r < 4; ++r) {
                int m = mbase + r;
                if (m < M) C[(size_t)m * F1 + n] = f2b(acc[mt][nt][r]);
            }
        }
    }
}

// ---------------------------------------------------------------------------
// MFMA bf16 GEMM (layer 2): C = A bf16 @ Bt^T  (+ R1's slot swizzle)
// ---------------------------------------------------------------------------
__global__ __launch_bounds__(256) void mfma_gemm_bt(const u16* __restrict__ A,
                                                    const u16* __restrict__ Bt,
                                                    u16* __restrict__ C,
                                                    int M, int N, int K) {
    __shared__ u16 sA[128 * 32];
    __shared__ u16 sB[128 * 32];
    int tid  = threadIdx.x;
    int wave = tid >> 6;
    int lane = tid & 63;
    int quad = lane >> 4;
    int lm   = lane & 15;
    int wm = wave & 1;
    int wn = wave >> 1;
    int m0 = blockIdx.y * 128;
    int n0 = blockIdx.x * 128;

    int ch0 = wave * 2, ch1 = wave * 2 + 1;
    int rsub = lane >> 2;
    int slot = (lane & 3) ^ ((lane >> 3) & 3);   // swizzled source slot
    int csub = slot * 8;
    int ar0 = min(m0 + ch0 * 16 + rsub, M - 1);
    int ar1 = min(m0 + ch1 * 16 + rsub, M - 1);
    int br0 = n0 + ch0 * 16 + rsub;
    int br1 = n0 + ch1 * 16 + rsub;
    const u16* gA0 = A + (size_t)ar0 * K + csub;
    const u16* gA1 = A + (size_t)ar1 * K + csub;
    const u16* gB0 = Bt + (size_t)br0 * K + csub;
    const u16* gB1 = Bt + (size_t)br1 * K + csub;

    f32x4 acc[4][4];
#pragma unroll
    for (int i = 0; i < 4; ++i)
#pragma unroll
        for (int j = 0; j < 4; ++j) acc[i][j] = (f32x4){0.f, 0.f, 0.f, 0.f};

    int rdoff = (quad ^ ((lm >> 1) & 3)) * 8;    // swizzled read slot

    for (int k0 = 0; k0 < K; k0 += 32) {
        gload_lds16(gA0 + k0, &sA[ch0 * 512]);
        gload_lds16(gA1 + k0, &sA[ch1 * 512]);
        gload_lds16(gB0 + k0, &sB[ch0 * 512]);
        gload_lds16(gB1 + k0, &sB[ch1 * 512]);
        __syncthreads();

        s16x8 af[4], bf[4];
#pragma unroll
        for (int mt = 0; mt < 4; ++mt)
            af[mt] = *(const s16x8*)&sA[(wm * 64 + mt * 16 + lm) * 32 + rdoff];
#pragma unroll
        for (int nt = 0; nt < 4; ++nt)
            bf[nt] = *(const s16x8*)&sB[(wn * 64 + nt * 16 + lm) * 32 + rdoff];
#pragma unroll
        for (int mt = 0; mt < 4; ++mt)
#pragma unroll
            for (int nt = 0; nt < 4; ++nt)
                acc[mt][nt] = __builtin_amdgcn_mfma_f32_16x16x32_bf16(
                    af[mt], bf[nt], acc[mt][nt], 0, 0, 0);
        __syncthreads();
    }

#pragma unroll
    for (int mt = 0; mt < 4; ++mt) {
        int mbase = m0 + wm * 64 + mt * 16 + quad * 4;
#pragma unroll
        for (int nt = 0; nt < 4; ++nt) {
            int n = n0 + wn * 64 + nt * 16 + lm;
#pragma unroll
            for (int r = 0; r < 4; ++r) {
                int m = mbase + r;
                if (m < M) C[(size_t)m * N + n] = f2b(acc[mt][nt][r]);
            }
        }
    }
}

// ---------------------------------------------------------------------------
// Per-node attention scores, bf16 h. One wave per node.
// ---------------------------------------------------------------------------
template <int F>
__global__ __launch_bounds__(256) void scores_bf16_kernel(const u16* __restrict__ h,
                                                          const float* __restrict__ a_src,
                                                          const float* __restrict__ a_dst,
                                                          float* __restrict__ s_src,
                                                          float* __restrict__ s_dst, int n) {
    int gwid = (blockIdx.x * blockDim.x + threadIdx.x) >> 6;
    int lane = threadIdx.x & 63;
    if (gwid >= n) return;
    const u32* row = (const u32*)(h + (size_t)gwid * F);
    float acc1 = 0.f, acc2 = 0.f;
    for (int p = lane; p < F / 2; p += 64) {
        u32 u = row[p];
        float v0 = b2f((u16)(u & 0xffff));
        float v1 = b2f((u16)(u >> 16));
        acc1 += v0 * a_src[2 * p] + v1 * a_src[2 * p + 1];
        acc2 += v0 * a_dst[2 * p] + v1 * a_dst[2 * p + 1];
    }
#pragma unroll
    for (int o = 32; o; o >>= 1) {
        acc1 += __shfl_xor(acc1, o);
        acc2 += __shfl_xor(acc2, o);
    }
    if (lane == 0) { s_src[gwid] = acc1; s_dst[gwid] = acc2; }
}

// fp32 variant (layer 3, F=NC)
template <int F>
__global__ __launch_bounds__(256) void scores_kernel(const float* __restrict__ h,
                                                     const float* __restrict__ a_src,
                                                     const float* __restrict__ a_dst,
                                                     float* __restrict__ s_src,
                                                     float* __restrict__ s_dst, int n) {
    int gwid = (blockIdx.x * blockDim.x + threadIdx.x) >> 6;
    int lane = threadIdx.x & 63;
    if (gwid >= n) return;
    const float* row = h + (size_t)gwid * F;
    float acc1 = 0.f, acc2 = 0.f;
    for (int f = lane; f < F; f += 64) {
        float v = row[f];
        acc1 += v * a_src[f];
        acc2 += v * a_dst[f];
    }
#pragma unroll
    for (int o = 32; o; o >>= 1) {
        acc1 += __shfl_xor(acc1, o);
        acc2 += __shfl_xor(acc2, o);
    }
    if (lane == 0) { s_src[gwid] = acc1; s_dst[gwid] = acc2; }
}

// ---------------------------------------------------------------------------
// CSR aggregation + segment softmax, bf16 h: ONE WAVE PER NODE, online
// softmax (running max m / denom with rescale). No LDS, no barriers, no
// MAXDEG cap, no serial wave-0 phase.
// ---------------------------------------------------------------------------
template <int F, bool OUT_BF16>
__global__ __launch_bounds__(256) void agg_online_kernel(
        const u16* __restrict__ h, const float* __restrict__ s_src,
        const float* __restrict__ s_dst, const float* __restrict__ bias,
        const int* __restrict__ row_ptr, const int* __restrict__ col,
        void* __restrict__ out, int n) {
    constexpr int UPL = F / 128;   // u32 per lane: 4 (F=512) or 2 (F=256)
    int gwid = (blockIdx.x * blockDim.x + threadIdx.x) >> 6;
    int lane = threadIdx.x & 63;
    if (gwid >= n) return;
    int beg = row_ptr[gwid];
    int end = row_ptr[gwid + 1];
    float sd = s_dst[gwid];
    const u32* hw = (const u32*)h;
    int loff = lane * UPL;

    float m = -1e30f, denom = 0.f;
    float acc[2 * UPL];
#pragma unroll
    for (int e = 0; e < 2 * UPL; ++e) acc[e] = 0.f;

    int j = beg;
    for (; j + 2 <= end; j += 2) {
        int c0 = col[j], c1 = col[j + 1];
        const u32* r0 = hw + (size_t)c0 * (F / 2) + loff;
        const u32* r1 = hw + (size_t)c1 * (F / 2) + loff;
        u32 v0[UPL], v1[UPL];
        if constexpr (UPL == 4) {
            uint4 q0 = *(const uint4*)r0; v0[0]=q0.x; v0[1]=q0.y; v0[2]=q0.z; v0[3]=q0.w;
            uint4 q1 = *(const uint4*)r1; v1[0]=q1.x; v1[1]=q1.y; v1[2]=q1.z; v1[3]=q1.w;
        } else {
            uint2 q0 = *(const uint2*)r0; v0[0]=q0.x; v0[1]=q0.y;
            uint2 q1 = *(const uint2*)r1; v1[0]=q1.x; v1[1]=q1.y;
        }
        float e0 = s_src[c0] + sd; e0 = (e0 > 0.f) ? e0 : NEG_SLOPE * e0;
        float e1 = s_src[c1] + sd; e1 = (e1 > 0.f) ? e1 : NEG_SLOPE * e1;
        float mn = fmaxf(fmaxf(m, e0), e1);
        float sc = expf(m - mn);
        float w0 = expf(e0 - mn);
        float w1 = expf(e1 - mn);
        denom = denom * sc + w0 + w1;
        m = mn;
#pragma unroll
        for (int u = 0; u < UPL; ++u) {
            acc[2*u]   = acc[2*u]   * sc + w0 * b2f((u16)(v0[u] & 0xffff))
                                         + w1 * b2f((u16)(v1[u] & 0xffff));
            acc[2*u+1] = acc[2*u+1] * sc + w0 * b2f((u16)(v0[u] >> 16))
                                         + w1 * b2f((u16)(v1[u] >> 16));
        }
    }
    if (j < end) {
        int c0 = col[j];
        const u32* r0 = hw + (size_t)c0 * (F / 2) + loff;
        u32 v0[UPL];
        if constexpr (UPL == 4) {
            uint4 q0 = *(const uint4*)r0; v0[0]=q0.x; v0[1]=q0.y; v0[2]=q0.z; v0[3]=q0.w;
        } else {
            uint2 q0 = *(const uint2*)r0; v0[0]=q0.x; v0[1]=q0.y;
        }
        float e0 = s_src[c0] + sd; e0 = (e0 > 0.f) ? e0 : NEG_SLOPE * e0;
        float mn = fmaxf(m, e0);
        float sc = expf(m - mn);
        float w0 = expf(e0 - mn);
        denom = denom * sc + w0;
        m = mn;
#pragma unroll
        for (int u = 0; u < UPL; ++u) {
            acc[2*u]   = acc[2*u]   * sc + w0 * b2f((u16)(v0[u] & 0xffff));
            acc[2*u+1] = acc[2*u+1] * sc + w0 * b2f((u16)(v0[u] >> 16));
        }
    }

    float inv = 1.0f / denom;
    if constexpr (OUT_BF16) {
        const float2* bp2 = (const float2*)bias;
        u32 ov[UPL];
#pragma unroll
        for (int u = 0; u < UPL; ++u) {
            float2 bb = bp2[loff + u];
            float v0 = fmaxf(acc[2*u]   * inv + bb.x, 0.f);
            float v1 = fmaxf(acc[2*u+1] * inv + bb.y, 0.f);
            ov[u] = pkbf16(v0, v1);
        }
        u32* op = (u32*)out + (size_t)gwid * (F / 2) + loff;
        if constexpr (UPL == 4) {
            uint4 q = {ov[0], ov[1], ov[2], ov[3]};
            *(uint4*)op = q;
        } else {
            uint2 q = {ov[0], ov[1]};
            *(uint2*)op = q;
        }
    } else {
        // UPL == 2: 4 consecutive f32 per lane
        const float* bp = bias + 2 * loff;
        float4 q = { fmaxf(acc[0] * inv + bp[0], 0.f),
                     fmaxf(acc[1] * inv + bp[1], 0.f),
                     fmaxf(acc[2] * inv + bp[2], 0.f),
                     fmaxf(acc[3] * inv + bp[3], 0.f) };
        *(float4*)((float*)out + (size_t)gwid * F + 2 * loff) = q;
    }
}

// ---------------------------------------------------------------------------
// Layer-3 aggregation: lane-per-edge, fused log_softmax. One wave per node.
// ---------------------------------------------------------------------------
__global__ __launch_bounds__(64) void agg_lsm7_kernel(const float* __restrict__ h,
                                                      const float* __restrict__ s_src,
                                                      const float* __restrict__ s_dst,
                                                      const float* __restrict__ bias,
                                                      const int* __restrict__ row_ptr,
                                                      const int* __restrict__ col,
                                                      float* __restrict__ out) {
    int node = blockIdx.x;
    int lane = threadIdx.x;
    int beg = row_ptr[node];
    int deg = min(row_ptr[node + 1] - beg, MAXDEG);

    __shared__ float w[MAXDEG];
    __shared__ int cs[MAXDEG];

    float sd = s_dst[node];
    float m = -1e30f;
    for (int j = lane; j < deg; j += 64) {
        int s = col[beg + j];
        cs[j] = s;
        float e = s_src[s] + sd;
        e = (e > 0.f) ? e : NEG_SLOPE * e;
        w[j] = e;
        m = fmaxf(m, e);
    }
#pragma unroll
    for (int o = 32; o; o >>= 1) m = fmaxf(m, __shfl_xor(m, o));
    float sum = 0.f;
    for (int j = lane; j < deg; j += 64) {
        float v = expf(w[j] - m);
        w[j] = v;
        sum += v;
    }
#pragma unroll
    for (int o = 32; o; o >>= 1) sum += __shfl_xor(sum, o);
    float inv = 1.0f / sum;

    float a[NC];
#pragma unroll
    for (int f = 0; f < NC; ++f) a[f] = 0.f;
    for (int j = lane; j < deg; j += 64) {
        float wg = w[j] * inv;
        const float* row = h + (size_t)cs[j] * NC;
#pragma unroll
        for (int f = 0; f < NC; ++f) a[f] += wg * row[f];
    }
#pragma unroll
    for (int f = 0; f < NC; ++f)
#pragma unroll
        for (int o = 32; o; o >>= 1) a[f] += __shfl_xor(a[f], o);

    if (lane == 0) {
        float vals[NC];
        float mx = -1e30f;
#pragma unroll
        for (int f = 0; f < NC; ++f) { vals[f] = a[f] + bias[f]; mx = fmaxf(mx, vals[f]); }
        float ssum = 0.f;
#pragma unroll
        for (int f = 0; f < NC; ++f) ssum += expf(vals[f] - mx);
        float lse = mx + logf(ssum);
#pragma unroll
        for (int f = 0; f < NC; ++f) out[(size_t)node * NC + f] = vals[f] - lse;
    }
}

// ---------------------------------------------------------------------------
// GEMM3: out[N,7] = A[N,256] f32 @ W[256,7] f32. One wave per node.
// ---------------------------------------------------------------------------
__global__ __launch_bounds__(256) void gemm3_kernel(const float* __restrict__ A,
                                                    const float* __restrict__ W,
                                                    float* __restrict__ out, int n) {
    __shared__ float sW[F2 * NC];
    for (int i = threadIdx.x; i < F2 * NC; i += blockDim.x) sW[i] = W[i];
    __syncthreads();
    int gwid = (blockIdx.x * blockDim.x + threadIdx.x) >> 6;
    int lane = threadIdx.x & 63;
    if (gwid >= n) return;
    const float* row = A + (size_t)gwid * F2;
    float4 v = *(const float4*)(row + lane * 4);
    float res = 0.f;
#pragma unroll
    for (int c = 0; c < NC; ++c) {
        float p = v.x * sW[(lane * 4 + 0) * NC + c] + v.y * sW[(lane * 4 + 1) * NC + c] +
                  v.z * sW[(lane * 4 + 2) * NC + c] + v.w * sW[(lane * 4 + 3) * NC + c];
#pragma unroll
        for (int o = 32; o; o >>= 1) p += __shfl_xor(p, o);
        if (lane == c) res = p;
    }
    if (lane < NC) out[(size_t)gwid * NC + lane] = res;
}

// ---------------------------------------------------------------------------
extern "C" void kernel_launch(void* const* d_in, const int* in_sizes, int n_in,
                              void* d_out, int out_size, void* d_ws, size_t ws_size,
                              hipStream_t stream) {
    const float* x   = (const float*)d_in[0];
    const int* ei    = (const int*)d_in[1];
    const int* src   = ei;
    const int* dst   = ei + E_EDGES;
    const float* W1  = (const float*)d_in[2];
    const float* as1 = (const float*)d_in[3];
    const float* ad1 = (const float*)d_in[4];
    const float* b1  = (const float*)d_in[5];
    const float* W2  = (const float*)d_in[6];
    const float* as2 = (const float*)d_in[7];
    const float* ad2 = (const float*)d_in[8];
    const float* b2  = (const float*)d_in[9];
    const float* W3  = (const float*)d_in[10];
    const float* as3 = (const float*)d_in[11];
    const float* ad3 = (const float*)d_in[12];
    const float* b3  = (const float*)d_in[13];
    float* outp = (float*)d_out;

    // ---------------- workspace layout (byte offsets) ----------------------
    char* base = (char*)d_ws;
    u16*  a1b = (u16*)base;                                   // [N][512]  bf16
    u16*  h2b = (u16*)(base + 51200000);                      // [N][256]  bf16
    float* a2 = (float*)(base + 76800000);                    // [N][256]  f32
    float* h3 = (float*)(base + 128000000);                   // [N][7]    f32
    u16*  h1b = (u16*)(base + 144000000);                     // [N][512]  bf16
    u16*  W1t = (u16*)(base + 195200000);                     // [512][1440] bf16
    u16*  W2t = (u16*)(base + 196674560);                     // [256][512]  bf16
    float* ssrc = (float*)(base + 196936704);                 // [N]
    float* sdst = (float*)(base + 197136704);                 // [N]
    int* row_ptr = (int*)(base + 197336704);                  // [N+1]
    int* counts  = (int*)(base + 197536708);                  // [N]
    int* fill    = (int*)(base + 197736708);                  // [N]
    int* col     = (int*)(base + 197936708);                  // [E_TOT]

    hipMemsetAsync(counts, 0, sizeof(int) * N_NODES, stream);
    hipMemsetAsync(fill, 0, sizeof(int) * N_NODES, stream);

    // CSR build
    {
        int blk = 256;
        int grid = (E_TOT + blk - 1) / blk;
        count_dst_kernel<<<grid, blk, 0, stream>>>(dst, counts);
        scan_kernel<<<1, 1024, 0, stream>>>(counts, row_ptr, N_NODES);
        scatter_kernel<<<grid, blk, 0, stream>>>(src, dst, row_ptr, fill, col);
    }

    // weight bf16 conversions
    {
        int nw1 = F1 * (KPAD1 / 2);
        convert_wt_kernel<<<(nw1 + 255) / 256, 256, 0, stream>>>(W1, (u32*)W1t, F_IN, F1, KPAD1);
        int nw2 = F2 * (F1 / 2);
        convert_wt_kernel<<<(nw2 + 255) / 256, 256, 0, stream>>>(W2, (u32*)W2t, F1, F2, F1);
    }

    int waves_grid = (N_NODES + 3) / 4;
    int mblocks = (N_NODES + 127) / 128;  // 391

    // ---- Layer 1 (fused f32->bf16 conversion)
    {
        dim3 grid1(2, (N_NODES + 63) / 64);  // 2 N-halves x 782 M-blocks
        gemm1_fused<<<grid1, 256, 0, stream>>>(x, W1t, h1b);
        scores_bf16_kernel<F1><<<waves_grid, 256, 0, stream>>>(h1b, as1, ad1, ssrc, sdst, N_NODES);
        agg_online_kernel<F1, true><<<waves_grid, 256, 0, stream>>>(
            h1b, ssrc, sdst, b1, row_ptr, col, a1b, N_NODES);
    }
    // ---- Layer 2
    {
        dim3 grid(F2 / 128, mblocks);
        mfma_gemm_bt<<<grid, 256, 0, stream>>>(a1b, W2t, h2b, N_NODES, F2, F1);
        scores_bf16_kernel<F2><<<waves_grid, 256, 0, stream>>>(h2b, as2, ad2, ssrc, sdst, N_NODES);
        agg_online_kernel<F2, false><<<waves_grid, 256, 0, stream>>>(
            h2b, ssrc, sdst, b2, row_ptr, col, a2, N_NODES);
    }
    // ---- Layer 3 (fp32)
    {
        gemm3_kernel<<<waves_grid, 256, 0, stream>>>(a2, W3, h3, N_NODES);
        scores_kernel<NC><<<waves_grid, 256, 0, stream>>>(h3, as3, ad3, ssrc, sdst, N_NODES);
        agg_lsm7_kernel<<<N_NODES, 64, 0, stream>>>(
            h3, ssrc, sdst, b3, row_ptr, col, outp);
    }
}

// Round 5
// 991.079 us; speedup vs baseline: 1.0653x; 1.0510x over previous
//
#include <hip/hip_runtime.h>
#include <hip/hip_bf16.h>
#include <math.h>

// Problem constants (from reference setup_inputs)
constexpr int N_NODES = 50000;
constexpr int E_EDGES = 800000;
constexpr int E_TOT   = E_EDGES + N_NODES;   // + self loops
constexpr int F_IN  = 1433;
constexpr int KPAD1 = 1440;                  // F_IN padded to mult of 32
constexpr int F1 = 512;
constexpr int F2 = 256;
constexpr int NC = 7;
constexpr float NEG_SLOPE = 0.2f;

typedef unsigned short u16;
typedef unsigned int   u32;
typedef short s16x8 __attribute__((ext_vector_type(8)));   // 8 bf16 = 4 VGPRs
typedef float f32x4 __attribute__((ext_vector_type(4)));
// x rows are 1433 f32 = 5732 B -> only 4-B aligned; reduced-alignment vec type
typedef float float4a __attribute__((ext_vector_type(4), aligned(4)));

__device__ inline u16 f2b(float f) {                 // fp32 -> bf16 bits, RNE
    u32 u = __float_as_uint(f);
    u32 r = (u + 0x7fffu + ((u >> 16) & 1u)) >> 16;
    return (u16)r;
}
__device__ inline float b2f(u16 b) { return __uint_as_float(((u32)b) << 16); }

__device__ inline u32 pkbf16(float lo, float hi) {   // v_cvt_pk_bf16_f32 (RNE)
    union { __hip_bfloat162 h; u32 u; } c;
    c.h = __float22bfloat162_rn(make_float2(lo, hi));
    return c.u;
}

__device__ inline void gload_lds16(const void* g, void* l) {
    __builtin_amdgcn_global_load_lds(
        (const __attribute__((address_space(1))) u32*)g,
        (__attribute__((address_space(3))) u32*)l, 16, 0, 0);
}

// Guarded 8-f32 load (columns >= F_IN read as exact 0). Plain loads:
// R3 showed non-temporal hints are a ~15% regression here.
__device__ inline void loadA8(const float* p, int gk, float4a& v0, float4a& v1) {
    if (gk + 8 <= F_IN) {
        v0 = *(const float4a*)p;
        v1 = *(const float4a*)(p + 4);
    } else {
#pragma unroll
        for (int i = 0; i < 4; ++i) v0[i] = (gk + i < F_IN) ? p[i] : 0.f;
#pragma unroll
        for (int i = 0; i < 4; ++i) v1[i] = (gk + 4 + i < F_IN) ? p[4 + i] : 0.f;
    }
}

// ---------------------------------------------------------------------------
// CSR build: histogram -> exclusive scan -> scatter
// ---------------------------------------------------------------------------
__global__ void count_dst_kernel(const int* __restrict__ dst, int* __restrict__ counts) {
    int i = blockIdx.x * blockDim.x + threadIdx.x;
    if (i < E_TOT) {
        int d = (i < E_EDGES) ? dst[i] : (i - E_EDGES);
        atomicAdd(&counts[d], 1);
    }
}

__global__ __launch_bounds__(1024) void scan_kernel(const int* __restrict__ counts,
                                                    int* __restrict__ row_ptr, int n) {
    __shared__ int part[1024];
    int t = threadIdx.x;
    int chunk = (n + 1023) / 1024;
    int lo = t * chunk;
    int hi = min(lo + chunk, n);
    int s = 0;
    for (int i = lo; i < hi; ++i) s += counts[i];
    part[t] = s;
    __syncthreads();
    for (int off = 1; off < 1024; off <<= 1) {
        int v = 0;
        if (t >= off) v = part[t - off];
        __syncthreads();
        part[t] += v;
        __syncthreads();
    }
    int run = part[t] - s;
    for (int i = lo; i < hi; ++i) { row_ptr[i] = run; run += counts[i]; }
    if (t == 1023) row_ptr[n] = part[1023];
}

__global__ void scatter_kernel(const int* __restrict__ src, const int* __restrict__ dst,
                               const int* __restrict__ row_ptr, int* __restrict__ fill,
                               int* __restrict__ col) {
    int i = blockIdx.x * blockDim.x + threadIdx.x;
    if (i < E_TOT) {
        int s = (i < E_EDGES) ? src[i] : (i - E_EDGES);
        int d = (i < E_EDGES) ? dst[i] : (i - E_EDGES);
        int p = row_ptr[d] + atomicAdd(&fill[d], 1);
        col[p] = s;
    }
}

// W [K][Nn] f32 -> Wt [Nn][KP] bf16 transposed (zero pad K)
__global__ void convert_wt_kernel(const float* __restrict__ W, u32* __restrict__ Wt,
                                  int K, int Nn, int KP) {
    int p = blockIdx.x * blockDim.x + threadIdx.x;
    int ppr = KP / 2;
    if (p >= Nn * ppr) return;
    int n = p / ppr;
    int k = (p - n * ppr) * 2;
    float v0 = (k + 0 < K) ? W[(size_t)(k + 0) * Nn + n] : 0.f;
    float v1 = (k + 1 < K) ? W[(size_t)(k + 1) * Nn + n] : 0.f;
    Wt[p] = (u32)f2b(v0) | ((u32)f2b(v1) << 16);
}

// ---------------------------------------------------------------------------
// Layer-1 fused GEMM: C[M][512](bf16) = A[M][1433](f32) @ W1t[512][1440]^T
// v6 = R1-v2 structure exactly (empirically fastest at 201us across R1-R4:
// runtime invariant to bank conflicts, vmcnt pipelining, nt hints, and 2x
// occupancy -> 64x512 with acc[4][8] amortizes A-staging best) + FUSED
// per-node attention scores epilogue: tile spans full N=512, so each block
// holds complete h-rows in f32 acc -> s_src/s_dst computed here (saves the
// scores_bf16<512> pass over 51 MB, and is MORE accurate than bf16 re-read).
// ---------------------------------------------------------------------------
__global__ __launch_bounds__(256, 2) void gemm1_fused(const float* __restrict__ A,
                                                      const u16* __restrict__ Bt,
                                                      u16* __restrict__ C,
                                                      const float* __restrict__ a_src,
                                                      const float* __restrict__ a_dst,
                                                      float* __restrict__ s_src,
                                                      float* __restrict__ s_dst) {
    constexpr int M = N_NODES;
    constexpr int ABUF = 64 * 32;     // u16 per A buffer (4 KB)
    constexpr int BBUF = 512 * 32;    // u16 per B buffer (32 KB)
    __shared__ u16 sA[2 * ABUF];
    __shared__ u16 sB[2 * BBUF];
    __shared__ float sRed[4][64][2];  // scores cross-wave reduce (2 KB)
    int tid  = threadIdx.x;
    int wave = tid >> 6;
    int lane = tid & 63;
    int quad = lane >> 4;
    int lm   = lane & 15;
    int m0 = blockIdx.x * 64;

    // ---- A staging: thread t owns row t>>2 (of 64), fetches swizzled slot
    int arow  = min(m0 + (tid >> 2), M - 1);
    int aslot = (tid & 3) ^ ((tid >> 3) & 3);          // global 8-f32 slot
    const float* xcol = A + (size_t)arow * F_IN + aslot * 8;
    int acolbase = aslot * 8;

    // ---- B staging: 32 chunks of (16 rows x 32 bf16 = 1 KB); wave w: 8w..8w+7
    const u16* gB[8];
    u16* lB[8];
#pragma unroll
    for (int c = 0; c < 8; ++c) {
        int chunk = wave * 8 + c;
        int row  = chunk * 16 + (lane >> 2);
        int slot = (lane & 3) ^ ((lane >> 3) & 3);
        gB[c] = Bt + (size_t)row * KPAD1 + slot * 8;
        lB[c] = &sB[chunk * 512];
    }

    f32x4 acc[4][8];
#pragma unroll
    for (int i = 0; i < 4; ++i)
#pragma unroll
        for (int j = 0; j < 8; ++j) acc[i][j] = (f32x4){0.f, 0.f, 0.f, 0.f};

    // swizzled read slot offset (u16 units) for fragment loads
    int rdoff = (quad ^ ((lm >> 1) & 3)) * 8;

    // ---- prologue: stage k=0 into buffer 0
    {
#pragma unroll
        for (int c = 0; c < 8; ++c) gload_lds16(gB[c], lB[c]);
        float4a a0, a1;
        loadA8(xcol, acolbase, a0, a1);
        uint4 pk;
        pk.x = pkbf16(a0[0], a0[1]); pk.y = pkbf16(a0[2], a0[3]);
        pk.z = pkbf16(a1[0], a1[1]); pk.w = pkbf16(a1[2], a1[3]);
        *(uint4*)&sA[tid * 8] = pk;
    }
    __syncthreads();

    int cur = 0;
    for (int k0 = 0; k0 < KPAD1; k0 += 32) {
        int kn = k0 + 32;
        bool hasnext = kn < KPAD1;
        int nxt = cur ^ 1;

        // issue next-step loads first (latency hides under current compute)
        float4a a0, a1;
        if (hasnext) {
#pragma unroll
            for (int c = 0; c < 8; ++c) gload_lds16(gB[c] + kn, lB[c] + nxt * BBUF);
            loadA8(xcol + kn, acolbase + kn, a0, a1);
        }

        // compute current buffer
        const u16* sAc = &sA[cur * ABUF];
        const u16* sBc = &sB[cur * BBUF];
        s16x8 af[4], bf[8];
#pragma unroll
        for (int mt = 0; mt < 4; ++mt)
            af[mt] = *(const s16x8*)&sAc[(mt * 16 + lm) * 32 + rdoff];
#pragma unroll
        for (int nt = 0; nt < 8; ++nt)
            bf[nt] = *(const s16x8*)&sBc[(wave * 128 + nt * 16 + lm) * 32 + rdoff];
#pragma unroll
        for (int mt = 0; mt < 4; ++mt)
#pragma unroll
            for (int nt = 0; nt < 8; ++nt)
                acc[mt][nt] = __builtin_amdgcn_mfma_f32_16x16x32_bf16(
                    af[mt], bf[nt], acc[mt][nt], 0, 0, 0);

        // write next A tile late (regs have arrived by now)
        if (hasnext) {
            uint4 pk;
            pk.x = pkbf16(a0[0], a0[1]); pk.y = pkbf16(a0[2], a0[3]);
            pk.z = pkbf16(a1[0], a1[1]); pk.w = pkbf16(a1[2], a1[3]);
            *(uint4*)&sA[nxt * ABUF + tid * 8] = pk;
        }
        __syncthreads();
        cur = nxt;
    }

    // C write: col = lane&15, row = quad*4 + reg
#pragma unroll
    for (int mt = 0; mt < 4; ++mt) {
        int mbase = m0 + mt * 16 + quad * 4;
#pragma unroll
        for (int nt = 0; nt < 8; ++nt) {
            int n = wave * 128 + nt * 16 + lm;
#pragma unroll
            for (int r = 0; r < 4; ++r) {
                int m = mbase + r;
                if (m < M) C[(size_t)m * F1 + n] = f2b(acc[mt][nt][r]);
            }
        }
    }

    // ---- fused scores epilogue: s = h . a over the full row held in acc
    float asn[8], adn[8];
#pragma unroll
    for (int nt = 0; nt < 8; ++nt) {
        int n = wave * 128 + nt * 16 + lm;
        asn[nt] = a_src[n];
        adn[nt] = a_dst[n];
    }
#pragma unroll
    for (int mt = 0; mt < 4; ++mt)
#pragma unroll
        for (int r = 0; r < 4; ++r) {
            float ps = 0.f, pd = 0.f;
#pragma unroll
            for (int nt = 0; nt < 8; ++nt) {
                ps += acc[mt][nt][r] * asn[nt];
                pd += acc[mt][nt][r] * adn[nt];
            }
#pragma unroll
            for (int o = 1; o < 16; o <<= 1) {
                ps += __shfl_xor(ps, o);
                pd += __shfl_xor(pd, o);
            }
            if (lm == 0) {
                int mloc = mt * 16 + quad * 4 + r;
                sRed[wave][mloc][0] = ps;
                sRed[wave][mloc][1] = pd;
            }
        }
    __syncthreads();
    if (tid < 64) {
        int m = m0 + tid;
        if (m < M) {
            s_src[m] = sRed[0][tid][0] + sRed[1][tid][0] + sRed[2][tid][0] + sRed[3][tid][0];
            s_dst[m] = sRed[0][tid][1] + sRed[1][tid][1] + sRed[2][tid][1] + sRed[3][tid][1];
        }
    }
}

// ---------------------------------------------------------------------------
// MFMA bf16 GEMM (layer 2): C = A bf16 @ Bt^T  (+ slot swizzle) + fused
// scores partials via atomicAdd (tile N=128 of 256 -> 2 partial adds/node).
// ---------------------------------------------------------------------------
__global__ __launch_bounds__(256) void mfma_gemm_bt(const u16* __restrict__ A,
                                                    const u16* __restrict__ Bt,
                                                    u16* __restrict__ C,
                                                    int M, int N, int K,
                                                    const float* __restrict__ a_src,
                                                    const float* __restrict__ a_dst,
                                                    float* __restrict__ s_src,
                                                    float* __restrict__ s_dst) {
    __shared__ u16 sA[128 * 32];
    __shared__ u16 sB[128 * 32];
    __shared__ float sRed[2][2][64][2];   // [wm][wn][mloc][{src,dst}]
    int tid  = threadIdx.x;
    int wave = tid >> 6;
    int lane = tid & 63;
    int quad = lane >> 4;
    int lm   = lane & 15;
    int wm = wave & 1;
    int wn = wave >> 1;
    int m0 = blockIdx.y * 128;
    int n0 = blockIdx.x * 128;

    int ch0 = wave * 2, ch1 = wave * 2 + 1;
    int rsub = lane >> 2;
    int slot = (lane & 3) ^ ((lane >> 3) & 3);   // swizzled source slot
    int csub = slot * 8;
    int ar0 = min(m0 + ch0 * 16 + rsub, M - 1);
    int ar1 = min(m0 + ch1 * 16 + rsub, M - 1);
    int br0 = n0 + ch0 * 16 + rsub;
    int br1 = n0 + ch1 * 16 + rsub;
    const u16* gA0 = A + (size_t)ar0 * K + csub;
    const u16* gA1 = A + (size_t)ar1 * K + csub;
    const u16* gB0 = Bt + (size_t)br0 * K + csub;
    const u16* gB1 = Bt + (size_t)br1 * K + csub;

    f32x4 acc[4][4];
#pragma unroll
    for (int i = 0; i < 4; ++i)
#pragma unroll
        for (int j = 0; j < 4; ++j) acc[i][j] = (f32x4){0.f, 0.f, 0.f, 0.f};

    int rdoff = (quad ^ ((lm >> 1) & 3)) * 8;    // swizzled read slot

    for (int k0 = 0; k0 < K; k0 += 32) {
        gload_lds16(gA0 + k0, &sA[ch0 * 512]);
        gload_lds16(gA1 + k0, &sA[ch1 * 512]);
        gload_lds16(gB0 + k0, &sB[ch0 * 512]);
        gload_lds16(gB1 + k0, &sB[ch1 * 512]);
        __syncthreads();

        s16x8 af[4], bf[4];
#pragma unroll
        for (int mt = 0; mt < 4; ++mt)
            af[mt] = *(const s16x8*)&sA[(wm * 64 + mt * 16 + lm) * 32 + rdoff];
#pragma unroll
        for (int nt = 0; nt < 4; ++nt)
            bf[nt] = *(const s16x8*)&sB[(wn * 64 + nt * 16 + lm) * 32 + rdoff];
#pragma unroll
        for (int mt = 0; mt < 4; ++mt)
#pragma unroll
            for (int nt = 0; nt < 4; ++nt)
                acc[mt][nt] = __builtin_amdgcn_mfma_f32_16x16x32_bf16(
                    af[mt], bf[nt], acc[mt][nt], 0, 0, 0);
        __syncthreads();
    }

#pragma unroll
    for (int mt = 0; mt < 4; ++mt) {
        int mbase = m0 + wm * 64 + mt * 16 + quad * 4;
#pragma unroll
        for (int nt = 0; nt < 4; ++nt) {
            int n = n0 + wn * 64 + nt * 16 + lm;
#pragma unroll
            for (int r = 0; r < 4; ++r) {
                int m = mbase + r;
                if (m < M) C[(size_t)m * N + n] = f2b(acc[mt][nt][r]);
            }
        }
    }

    // ---- fused scores partials (this block covers n0..n0+127 of each row)
    float asn[4], adn[4];
#pragma unroll
    for (int nt = 0; nt < 4; ++nt) {
        int n = n0 + wn * 64 + nt * 16 + lm;
        asn[nt] = a_src[n];
        adn[nt] = a_dst[n];
    }
#pragma unroll
    for (int mt = 0; mt < 4; ++mt)
#pragma unroll
        for (int r = 0; r < 4; ++r) {
            float ps = 0.f, pd = 0.f;
#pragma unroll
            for (int nt = 0; nt < 4; ++nt) {
                ps += acc[mt][nt][r] * asn[nt];
                pd += acc[mt][nt][r] * adn[nt];
            }
#pragma unroll
            for (int o = 1; o < 16; o <<= 1) {
                ps += __shfl_xor(ps, o);
                pd += __shfl_xor(pd, o);
            }
            if (lm == 0) {
                int mloc = mt * 16 + quad * 4 + r;
                sRed[wm][wn][mloc][0] = ps;
                sRed[wm][wn][mloc][1] = pd;
            }
        }
    __syncthreads();
    if (tid < 128) {
        int wmf = tid >> 6, mloc = tid & 63;
        int m = m0 + wmf * 64 + mloc;
        if (m < M) {
            atomicAdd(&s_src[m], sRed[wmf][0][mloc][0] + sRed[wmf][1][mloc][0]);
            atomicAdd(&s_dst[m], sRed[wmf][0][mloc][1] + sRed[wmf][1][mloc][1]);
        }
    }
}

// ---------------------------------------------------------------------------
// CSR aggregation + segment softmax, bf16 h: ONE WAVE PER NODE, online
// softmax (running max m / denom with rescale). No LDS, no barriers.
// ---------------------------------------------------------------------------
template <int F, bool OUT_BF16>
__global__ __launch_bounds__(256) void agg_online_kernel(
        const u16* __restrict__ h, const float* __restrict__ s_src,
        const float* __restrict__ s_dst, const float* __restrict__ bias,
        const int* __restrict__ row_ptr, const int* __restrict__ col,
        void* __restrict__ out, int n) {
    constexpr int UPL = F / 128;   // u32 per lane: 4 (F=512) or 2 (F=256)
    int gwid = (blockIdx.x * blockDim.x + threadIdx.x) >> 6;
    int lane = threadIdx.x & 63;
    if (gwid >= n) return;
    int beg = row_ptr[gwid];
    int end = row_ptr[gwid + 1];
    float sd = s_dst[gwid];
    const u32* hw = (const u32*)h;
    int loff = lane * UPL;

    float m = -1e30f, denom = 0.f;
    float acc[2 * UPL];
#pragma unroll
    for (int e = 0; e < 2 * UPL; ++e) acc[e] = 0.f;

    int j = beg;
    for (; j + 2 <= end; j += 2) {
        int c0 = col[j], c1 = col[j + 1];
        const u32* r0 = hw + (size_t)c0 * (F / 2) + loff;
        const u32* r1 = hw + (size_t)c1 * (F / 2) + loff;
        u32 v0[UPL], v1[UPL];
        if constexpr (UPL == 4) {
            uint4 q0 = *(const uint4*)r0; v0[0]=q0.x; v0[1]=q0.y; v0[2]=q0.z; v0[3]=q0.w;
            uint4 q1 = *(const uint4*)r1; v1[0]=q1.x; v1[1]=q1.y; v1[2]=q1.z; v1[3]=q1.w;
        } else {
            uint2 q0 = *(const uint2*)r0; v0[0]=q0.x; v0[1]=q0.y;
            uint2 q1 = *(const uint2*)r1; v1[0]=q1.x; v1[1]=q1.y;
        }
        float e0 = s_src[c0] + sd; e0 = (e0 > 0.f) ? e0 : NEG_SLOPE * e0;
        float e1 = s_src[c1] + sd; e1 = (e1 > 0.f) ? e1 : NEG_SLOPE * e1;
        float mn = fmaxf(fmaxf(m, e0), e1);
        float sc = expf(m - mn);
        float w0 = expf(e0 - mn);
        float w1 = expf(e1 - mn);
        denom = denom * sc + w0 + w1;
        m = mn;
#pragma unroll
        for (int u = 0; u < UPL; ++u) {
            acc[2*u]   = acc[2*u]   * sc + w0 * b2f((u16)(v0[u] & 0xffff))
                                         + w1 * b2f((u16)(v1[u] & 0xffff));
            acc[2*u+1] = acc[2*u+1] * sc + w0 * b2f((u16)(v0[u] >> 16))
                                         + w1 * b2f((u16)(v1[u] >> 16));
        }
    }
    if (j < end) {
        int c0 = col[j];
        const u32* r0 = hw + (size_t)c0 * (F / 2) + loff;
        u32 v0[UPL];
        if constexpr (UPL == 4) {
            uint4 q0 = *(const uint4*)r0; v0[0]=q0.x; v0[1]=q0.y; v0[2]=q0.z; v0[3]=q0.w;
        } else {
            uint2 q0 = *(const uint2*)r0; v0[0]=q0.x; v0[1]=q0.y;
        }
        float e0 = s_src[c0] + sd; e0 = (e0 > 0.f) ? e0 : NEG_SLOPE * e0;
        float mn = fmaxf(m, e0);
        float sc = expf(m - mn);
        float w0 = expf(e0 - mn);
        denom = denom * sc + w0;
        m = mn;
#pragma unroll
        for (int u = 0; u < UPL; ++u) {
            acc[2*u]   = acc[2*u]   * sc + w0 * b2f((u16)(v0[u] & 0xffff));
            acc[2*u+1] = acc[2*u+1] * sc + w0 * b2f((u16)(v0[u] >> 16));
        }
    }

    float inv = 1.0f / denom;
    if constexpr (OUT_BF16) {
        const float2* bp2 = (const float2*)bias;
        u32 ov[UPL];
#pragma unroll
        for (int u = 0; u < UPL; ++u) {
            float2 bb = bp2[loff + u];
            float v0 = fmaxf(acc[2*u]   * inv + bb.x, 0.f);
            float v1 = fmaxf(acc[2*u+1] * inv + bb.y, 0.f);
            ov[u] = pkbf16(v0, v1);
        }
        u32* op = (u32*)out + (size_t)gwid * (F / 2) + loff;
        if constexpr (UPL == 4) {
            uint4 q = {ov[0], ov[1], ov[2], ov[3]};
            *(uint4*)op = q;
        } else {
            uint2 q = {ov[0], ov[1]};
            *(uint2*)op = q;
        }
    } else {
        // UPL == 2: 4 consecutive f32 per lane
        const float* bp = bias + 2 * loff;
        float4 q = { fmaxf(acc[0] * inv + bp[0], 0.f),
                     fmaxf(acc[1] * inv + bp[1], 0.f),
                     fmaxf(acc[2] * inv + bp[2], 0.f),
                     fmaxf(acc[3] * inv + bp[3], 0.f) };
        *(float4*)((float*)out + (size_t)gwid * F + 2 * loff) = q;
    }
}

// ---------------------------------------------------------------------------
// Layer-3 aggregation: ONE WAVE PER NODE, online softmax in registers
// (7 accumulators), butterfly wave-combine, fused log_softmax. No LDS.
// ---------------------------------------------------------------------------
__global__ __launch_bounds__(256) void agg_lsm7_kernel(const float* __restrict__ h,
                                                       const float* __restrict__ s_src,
                                                       const float* __restrict__ s_dst,
                                                       const float* __restrict__ bias,
                                                       const int* __restrict__ row_ptr,
                                                       const int* __restrict__ col,
                                                       float* __restrict__ out, int n) {
    int gwid = (blockIdx.x * blockDim.x + threadIdx.x) >> 6;
    int lane = threadIdx.x & 63;
    if (gwid >= n) return;
    int beg = row_ptr[gwid];
    int end = row_ptr[gwid + 1];
    float sd = s_dst[gwid];

    float m = -1e30f, denom = 0.f;
    float a[NC];
#pragma unroll
    for (int f = 0; f < NC; ++f) a[f] = 0.f;

    for (int j = beg + lane; j < end; j += 64) {
        int c = col[j];
        float e = s_src[c] + sd;
        e = (e > 0.f) ? e : NEG_SLOPE * e;
        float mn = fmaxf(m, e);
        float sc = expf(m - mn);
        float w = expf(e - mn);
        denom = denom * sc + w;
        m = mn;
        const float* hr = h + (size_t)c * NC;
#pragma unroll
        for (int f = 0; f < NC; ++f) a[f] = a[f] * sc + w * hr[f];
    }
    // butterfly combine across 64 lanes (online-merge of (m, denom, a[]))
#pragma unroll
    for (int o = 32; o; o >>= 1) {
        float mo = __shfl_xor(m, o);
        float dn = __shfl_xor(denom, o);
        float M2 = fmaxf(m, mo);
        float s1 = expf(m - M2);
        float s2 = expf(mo - M2);
        denom = denom * s1 + dn * s2;
#pragma unroll
        for (int f = 0; f < NC; ++f) {
            float af = __shfl_xor(a[f], o);
            a[f] = a[f] * s1 + af * s2;
        }
        m = M2;
    }

    if (lane == 0) {
        float inv = 1.0f / denom;
        float vals[NC];
        float mx = -1e30f;
#pragma unroll
        for (int f = 0; f < NC; ++f) {
            vals[f] = a[f] * inv + bias[f];
            mx = fmaxf(mx, vals[f]);
        }
        float ssum = 0.f;
#pragma unroll
        for (int f = 0; f < NC; ++f) ssum += expf(vals[f] - mx);
        float lse = mx + logf(ssum);
#pragma unroll
        for (int f = 0; f < NC; ++f) out[(size_t)gwid * NC + f] = vals[f] - lse;
    }
}

// ---------------------------------------------------------------------------
// GEMM3: out[N,7] = A[N,256] f32 @ W[256,7] f32 + fused scores. One wave/node.
// ---------------------------------------------------------------------------
__global__ __launch_bounds__(256) void gemm3_kernel(const float* __restrict__ A,
                                                    const float* __restrict__ W,
                                                    float* __restrict__ out, int n,
                                                    const float* __restrict__ a_src,
                                                    const float* __restrict__ a_dst,
                                                    float* __restrict__ s_src,
                                                    float* __restrict__ s_dst) {
    __shared__ float sW[F2 * NC];
    for (int i = threadIdx.x; i < F2 * NC; i += blockDim.x) sW[i] = W[i];
    __syncthreads();
    int gwid = (blockIdx.x * blockDim.x + threadIdx.x) >> 6;
    int lane = threadIdx.x & 63;
    if (gwid >= n) return;
    const float* row = A + (size_t)gwid * F2;
    float4 v = *(const float4*)(row + lane * 4);
    float res = 0.f;
#pragma unroll
    for (int c = 0; c < NC; ++c) {
        float p = v.x * sW[(lane * 4 + 0) * NC + c] + v.y * sW[(lane * 4 + 1) * NC + c] +
                  v.z * sW[(lane * 4 + 2) * NC + c] + v.w * sW[(lane * 4 + 3) * NC + c];
#pragma unroll
        for (int o = 32; o; o >>= 1) p += __shfl_xor(p, o);
        if (lane == c) res = p;
    }
    if (lane < NC) out[(size_t)gwid * NC + lane] = res;
    // fused scores: lanes 0..6 hold h3[gwid][lane]
    float p1 = (lane < NC) ? res * a_src[lane] : 0.f;
    float p2 = (lane < NC) ? res * a_dst[lane] : 0.f;
#pragma unroll
    for (int o = 1; o < 8; o <<= 1) {
        p1 += __shfl_xor(p1, o);
        p2 += __shfl_xor(p2, o);
    }
    if (lane == 0) { s_src[gwid] = p1; s_dst[gwid] = p2; }
}

// ---------------------------------------------------------------------------
extern "C" void kernel_launch(void* const* d_in, const int* in_sizes, int n_in,
                              void* d_out, int out_size, void* d_ws, size_t ws_size,
                              hipStream_t stream) {
    const float* x   = (const float*)d_in[0];
    const int* ei    = (const int*)d_in[1];
    const int* src   = ei;
    const int* dst   = ei + E_EDGES;
    const float* W1  = (const float*)d_in[2];
    const float* as1 = (const float*)d_in[3];
    const float* ad1 = (const float*)d_in[4];
    const float* b1  = (const float*)d_in[5];
    const float* W2  = (const float*)d_in[6];
    const float* as2 = (const float*)d_in[7];
    const float* ad2 = (const float*)d_in[8];
    const float* b2  = (const float*)d_in[9];
    const float* W3  = (const float*)d_in[10];
    const float* as3 = (const float*)d_in[11];
    const float* ad3 = (const float*)d_in[12];
    const float* b3  = (const float*)d_in[13];
    float* outp = (float*)d_out;

    // ---------------- workspace layout (byte offsets) ----------------------
    char* base = (char*)d_ws;
    u16*  a1b = (u16*)base;                                   // [N][512]  bf16
    u16*  h2b = (u16*)(base + 51200000);                      // [N][256]  bf16
    float* a2 = (float*)(base + 76800000);                    // [N][256]  f32
    float* h3 = (float*)(base + 128000000);                   // [N][7]    f32
    u16*  h1b = (u16*)(base + 144000000);                     // [N][512]  bf16
    u16*  W1t = (u16*)(base + 195200000);                     // [512][1440] bf16
    u16*  W2t = (u16*)(base + 196674560);                     // [256][512]  bf16
    float* ssrc = (float*)(base + 196936704);                 // [N]
    float* sdst = (float*)(base + 197136704);                 // [N]
    int* row_ptr = (int*)(base + 197336704);                  // [N+1]
    int* counts  = (int*)(base + 197536708);                  // [N]
    int* fill    = (int*)(base + 197736708);                  // [N]
    int* col     = (int*)(base + 197936708);                  // [E_TOT]

    hipMemsetAsync(counts, 0, sizeof(int) * N_NODES, stream);
    hipMemsetAsync(fill, 0, sizeof(int) * N_NODES, stream);

    // CSR build
    {
        int blk = 256;
        int grid = (E_TOT + blk - 1) / blk;
        count_dst_kernel<<<grid, blk, 0, stream>>>(dst, counts);
        scan_kernel<<<1, 1024, 0, stream>>>(counts, row_ptr, N_NODES);
        scatter_kernel<<<grid, blk, 0, stream>>>(src, dst, row_ptr, fill, col);
    }

    // weight bf16 conversions
    {
        int nw1 = F1 * (KPAD1 / 2);
        convert_wt_kernel<<<(nw1 + 255) / 256, 256, 0, stream>>>(W1, (u32*)W1t, F_IN, F1, KPAD1);
        int nw2 = F2 * (F1 / 2);
        convert_wt_kernel<<<(nw2 + 255) / 256, 256, 0, stream>>>(W2, (u32*)W2t, F1, F2, F1);
    }

    int waves_grid = (N_NODES + 3) / 4;
    int mblocks = (N_NODES + 127) / 128;  // 391

    // ---- Layer 1 (fused conversion + scores epilogue)
    {
        int grid1 = (N_NODES + 63) / 64;  // 782
        gemm1_fused<<<grid1, 256, 0, stream>>>(x, W1t, h1b, as1, ad1, ssrc, sdst);
        agg_online_kernel<F1, true><<<waves_grid, 256, 0, stream>>>(
            h1b, ssrc, sdst, b1, row_ptr, col, a1b, N_NODES);
    }
    // ---- Layer 2 (fused scores partials via atomicAdd)
    {
        hipMemsetAsync(ssrc, 0, sizeof(float) * N_NODES, stream);
        hipMemsetAsync(sdst, 0, sizeof(float) * N_NODES, stream);
        dim3 grid(F2 / 128, mblocks);
        mfma_gemm_bt<<<grid, 256, 0, stream>>>(a1b, W2t, h2b, N_NODES, F2, F1,
                                               as2, ad2, ssrc, sdst);
        agg_online_kernel<F2, false><<<waves_grid, 256, 0, stream>>>(
            h2b, ssrc, sdst, b2, row_ptr, col, a2, N_NODES);
    }
    // ---- Layer 3 (fp32, fused scores in gemm3)
    {
        gemm3_kernel<<<waves_grid, 256, 0, stream>>>(a2, W3, h3, N_NODES,
                                                     as3, ad3, ssrc, sdst);
        agg_lsm7_kernel<<<waves_grid, 256, 0, stream>>>(
            h3, ssrc, sdst, b3, row_ptr, col, outp, N_NODES);
    }
}